// Round 9
// baseline (343.059 us; speedup 1.0000x reference)
//
#include <hip/hip_runtime.h>
#include <math.h>

#define B 8
#define S 1024
#define D 768
#define H 12
#define V 50257
#define DFF 3072
#define HD (H*D)      // 9216
#define SLO 1012      // first s needed (head 11, last 12 positions of y feed x row 1023)
#define NS 12

// workspace layout (float offsets)
#define OFF_EMEAN 0                     // 768   (atomic sum; divide by V on read)
#define OFF_A     768                   // B*NS*D = 73728 (atomic)
#define OFF_GQ    (OFF_A + B*NS*D)      // NS*D = 9216 (unused; kept for layout)
#define OFF_SC    (OFF_GQ + NS*D)       // NS*S = 12288 (raw scores)
#define OFF_YV    (OFF_SC + NS*S)       // B*HD = 73728 (unused; kept for layout)
#define OFF_YO    (OFF_YV + B*HD)       // B*D = 6144 (atomic)
#define OFF_G     (OFF_YO + B*D)        // B*DFF = 24576
#define OFF_X     (OFF_G + B*DFF)       // B*D = 6144 (atomic)

typedef float f4 __attribute__((ext_vector_type(4)));

__device__ __forceinline__ float wsum(float v) {
    v += __shfl_xor(v, 1, 64);
    v += __shfl_xor(v, 2, 64);
    v += __shfl_xor(v, 4, 64);
    v += __shfl_xor(v, 8, 64);
    v += __shfl_xor(v, 16, 64);
    v += __shfl_xor(v, 32, 64);
    return v;
}

__device__ __forceinline__ float wmax(float v) {
    v = fmaxf(v, __shfl_xor(v, 1, 64));
    v = fmaxf(v, __shfl_xor(v, 2, 64));
    v = fmaxf(v, __shfl_xor(v, 4, 64));
    v = fmaxf(v, __shfl_xor(v, 8, 64));
    v = fmaxf(v, __shfl_xor(v, 16, 64));
    v = fmaxf(v, __shfl_xor(v, 32, 64));
    return v;
}

// ---- K14: fused e_mean column-sum (k1 role) + softmax-inline attention
//      gather-accumulate (k4 role).
// k1 role: r7's best-measured shape (scalar-column, contiguous spans, counted
// vmcnt(8) double-batch). Shape space exhausted (5 variants, all ~1.7-2 TB/s
// effective) — frozen.
#define K14_K4_BLOCKS 256             // (32 tc, 8 b)
#define K14_K1_BLOCKS 512
#define K1_ROWS 99                    // 512*99 = 50688 >= V; batches/block = 12 or 8 (even)

#define K1_ISSUE8(T0,T1,T2,T3,T4,T5,T6,T7, P) do {                         \
    const float* _q = (P);                                                 \
    asm volatile("global_load_dword %0, %1, off" : "=v"(T0) : "v"(_q));    \
    asm volatile("global_load_dword %0, %1, off" : "=v"(T1) : "v"(_q + 1*D)); \
    asm volatile("global_load_dword %0, %1, off" : "=v"(T2) : "v"(_q + 2*D)); \
    asm volatile("global_load_dword %0, %1, off" : "=v"(T3) : "v"(_q + 3*D)); \
    asm volatile("global_load_dword %0, %1, off" : "=v"(T4) : "v"(_q + 4*D)); \
    asm volatile("global_load_dword %0, %1, off" : "=v"(T5) : "v"(_q + 5*D)); \
    asm volatile("global_load_dword %0, %1, off" : "=v"(T6) : "v"(_q + 6*D)); \
    asm volatile("global_load_dword %0, %1, off" : "=v"(T7) : "v"(_q + 7*D)); \
} while (0)

#define K1_WAIT(N, T0,T1,T2,T3,T4,T5,T6,T7) do {                           \
    asm volatile("s_waitcnt vmcnt(" #N ")"                                 \
                 : "+v"(T0), "+v"(T1), "+v"(T2), "+v"(T3),                 \
                   "+v"(T4), "+v"(T5), "+v"(T6), "+v"(T7)                  \
                 :                                                         \
                 : "memory");                                              \
    __builtin_amdgcn_sched_barrier(0);                                     \
} while (0)

__global__ __launch_bounds__(768) void k14_emean_accA(const int* __restrict__ idx,
                                                      const float* __restrict__ wte,
                                                      float* __restrict__ ws) {
    __shared__ float wl[32 * 12];
    __shared__ float mxs[12], invs[12];
    const int bid = blockIdx.x;
    const int tid = threadIdx.x;                              // 0..767 (float column)
    if (bid >= K14_K4_BLOCKS) {
        // ---- k1 role: column sums of wte rows [r0, r1)
        const int kb = bid - K14_K4_BLOCKS;
        int r0 = kb * K1_ROWS;
        if (r0 >= V) return;
        int r1 = r0 + K1_ROWS; if (r1 > V) r1 = V;
        const float* __restrict__ p = wte + (size_t)r0 * D + tid;
        const int nfull = (r1 - r0) >> 3;                     // 12 or 8 (even, >=2)
        float a0 = 0.f, a1 = 0.f, a2 = 0.f, a3 = 0.f;
        float a4 = 0.f, a5 = 0.f, a6 = 0.f, a7 = 0.f;
        float t0, t1, t2, t3, t4, t5, t6, t7;
        float u0, u1, u2, u3, u4, u5, u6, u7;
        K1_ISSUE8(t0,t1,t2,t3,t4,t5,t6,t7, p); p += 8 * D;
        for (int b2 = 0; b2 + 2 < nfull; b2 += 2) {
            K1_ISSUE8(u0,u1,u2,u3,u4,u5,u6,u7, p); p += 8 * D;
            K1_WAIT(8, t0,t1,t2,t3,t4,t5,t6,t7);
            a0 += t0; a1 += t1; a2 += t2; a3 += t3;
            a4 += t4; a5 += t5; a6 += t6; a7 += t7;
            K1_ISSUE8(t0,t1,t2,t3,t4,t5,t6,t7, p); p += 8 * D;
            K1_WAIT(8, u0,u1,u2,u3,u4,u5,u6,u7);
            a0 += u0; a1 += u1; a2 += u2; a3 += u3;
            a4 += u4; a5 += u5; a6 += u6; a7 += u7;
        }
        K1_ISSUE8(u0,u1,u2,u3,u4,u5,u6,u7, p); p += 8 * D;
        K1_WAIT(8, t0,t1,t2,t3,t4,t5,t6,t7);
        a0 += t0; a1 += t1; a2 += t2; a3 += t3;
        a4 += t4; a5 += t5; a6 += t6; a7 += t7;
        K1_WAIT(0, u0,u1,u2,u3,u4,u5,u6,u7);
        a0 += u0; a1 += u1; a2 += u2; a3 += u3;
        a4 += u4; a5 += u5; a6 += u6; a7 += u7;
        for (int r = r0 + nfull * 8; r < r1; ++r) { a0 += *p; p += D; }
        a0 += a1 + a2 + a3 + a4 + a5 + a6 + a7;
        atomicAdd(&ws[OFF_EMEAN + tid], a0);
    } else {
        // ---- k4 role: A[b,s12,:] += sum_t attn[s12,t]*wte[idx[b,t],:]
        // (softmax recomputed in-block from raw scores; k3 launch deleted)
        const int tc = bid & 31, b = bid >> 5;
        const int w = tid >> 6, lane = tid & 63;              // wave w owns row w
        {
            const int n = SLO + w + 1;
            const float* __restrict__ sc = ws + OFF_SC + w * S;
            float m = -1e30f;
#pragma unroll
            for (int kk = 0; kk < 16; ++kk) {
                int t = kk * 64 + lane;
                if (t < n) m = fmaxf(m, sc[t]);
            }
            m = wmax(m);
            float ssum = 0.f;
#pragma unroll
            for (int kk = 0; kk < 16; ++kk) {
                int t = kk * 64 + lane;
                if (t < n) ssum += expf(sc[t] - m);
            }
            ssum = wsum(ssum);
            if (lane == 0) { mxs[w] = m; invs[w] = 1.0f / ssum; }
        }
        __syncthreads();
        if (tid < 384) {
            int tl = tid / 12, s12 = tid % 12;
            int t = tc * 32 + tl;
            float raw = ws[OFF_SC + s12 * S + t];
            wl[tid] = (t < SLO + s12 + 1) ? expf(raw - mxs[s12]) * invs[s12] : 0.0f;
        }
        __syncthreads();
        float acc[12] = {0,0,0,0,0,0,0,0,0,0,0,0};
        const int* __restrict__ ib = idx + b * S + tc * 32;
#pragma unroll 4
        for (int tl = 0; tl < 32; ++tl) {
            int row = ib[tl];
            float val = wte[(size_t)row * D + tid];
            const float* wgt = &wl[tl * 12];
#pragma unroll
            for (int s12 = 0; s12 < 12; ++s12) acc[s12] += wgt[s12] * val;
        }
#pragma unroll
        for (int s12 = 0; s12 < 12; ++s12)
            atomicAdd(&ws[OFF_A + (b * NS + s12) * D + tid], acc[s12]);
    }
}

// ---- K2b: scores[s12,t] = p[t,:] . (wpe[SLO+s12+1,:]*wq[11,:]*wk[11,:]).
// Tail blocks zero the atomic regions: [em|A] (291 blocks) and YO (24 blocks).
// grid 571 x 256
#define K2B_ZBLOCKS 315               // 291 (em+A contiguous) + 24 (YO)
__global__ __launch_bounds__(256) void k2b_scores(const float* __restrict__ wpe,
                                                  const float* __restrict__ wq,
                                                  const float* __restrict__ wk,
                                                  float* __restrict__ ws) {
    if (blockIdx.x >= 256) {
        int zb = blockIdx.x - 256;
        if (zb < 291) {
            int i = zb * 256 + threadIdx.x;                   // < 74496 = em + A
            ws[OFF_EMEAN + i] = 0.0f;
        } else {
            int i = (zb - 291) * 256 + threadIdx.x;           // < 6144 = YO
            ws[OFF_YO + i] = 0.0f;
        }
        return;
    }
    const int lane = threadIdx.x & 63;
    const int t = (blockIdx.x * 256 + threadIdx.x) >> 6;      // 0..1023
    float4 pw[3];                                             // p[t] * wq[11] * wk[11]
#pragma unroll
    for (int i = 0; i < 3; ++i) {
        int col = 4 * lane + 256 * i;
        float4 p = *reinterpret_cast<const float4*>(wpe + t * D + col);
        float4 q = *reinterpret_cast<const float4*>(wq + 11 * D + col);
        float4 k = *reinterpret_cast<const float4*>(wk + 11 * D + col);
        pw[i].x = p.x * q.x * k.x;
        pw[i].y = p.y * q.y * k.y;
        pw[i].z = p.z * q.z * k.z;
        pw[i].w = p.w * q.w * k.w;
    }
    float acc[12];
#pragma unroll
    for (int s12 = 0; s12 < 12; ++s12) {
        float a = 0.f;
#pragma unroll
        for (int i = 0; i < 3; ++i) {
            float4 g = *reinterpret_cast<const float4*>(wpe + (SLO + s12 + 1) * D + 4 * lane + 256 * i);
            a += pw[i].x * g.x + pw[i].y * g.y + pw[i].z * g.z + pw[i].w * g.w;
        }
        acc[s12] = a;
    }
#pragma unroll
    for (int s12 = 0; s12 < 12; ++s12) acc[s12] = wsum(acc[s12]);
    float v = acc[0];
#pragma unroll
    for (int j = 1; j < 12; ++j) if (lane == j) v = acc[j];
    if (lane < 12) ws[OFF_SC + lane * S + t] = v;
}

// ---- K6: yo[b,d'] += sum_f w_o[d',f] * yv[b,f], with
//      yv[b, s12*768+d] = (A[b,s12,d] - em[d])*wv[11,d]*invn[s12]*wlr[11]
// computed inline (k5 deleted). Wave per (row-pair, kc=s12).
// Tail blocks (1152..1154) atomicAdd the sb term into yo. grid 1155 x 256
__global__ __launch_bounds__(256) void k6_wo(const int* __restrict__ idx,
                                             const float* __restrict__ wte,
                                             const float* __restrict__ w_o,
                                             const float* __restrict__ wv,
                                             const float* __restrict__ wlr,
                                             float* __restrict__ ws) {
    if (blockIdx.x >= 1152) {
        int d = (blockIdx.x - 1152) * 256 + threadIdx.x;      // < 768
        float em = ws[OFF_EMEAN + d] * (1.0f / V);
        float s = 0.f;
#pragma unroll
        for (int b = 0; b < 8; ++b) {
            int row = idx[b * S + (S - 1)];
            s += wte[(size_t)row * D + d];
        }
        float sb = (s - 8.0f * em) * (1.0f / (float)S);
#pragma unroll
        for (int b = 0; b < 8; ++b) atomicAdd(&ws[OFF_YO + b * D + d], sb);
        return;
    }
    const int lane = threadIdx.x & 63;
    const int wid = (blockIdx.x * 256 + threadIdx.x) >> 6;    // 0..4607
    const int kc = wid % 12;                                  // = s12
    const int r0 = (wid / 12) * 2;                            // 0..766
    const float c1 = (1.0f / (float)(SLO + kc + 1)) * wlr[11];
    float acc[2][8] = {{0}};
#pragma unroll
    for (int i = 0; i < 3; ++i) {
        int d = 4 * lane + 256 * i;
        int k = kc * 768 + d;
        float4 a0 = *reinterpret_cast<const float4*>(w_o + (size_t)r0 * HD + k);
        float4 a1 = *reinterpret_cast<const float4*>(w_o + (size_t)(r0 + 1) * HD + k);
        float4 em4 = *reinterpret_cast<const float4*>(ws + OFF_EMEAN + d);
        float4 wv4 = *reinterpret_cast<const float4*>(wv + 11 * D + d);
        float4 cm;
        cm.x = wv4.x * c1; cm.y = wv4.y * c1; cm.z = wv4.z * c1; cm.w = wv4.w * c1;
        em4.x *= (1.0f / V); em4.y *= (1.0f / V); em4.z *= (1.0f / V); em4.w *= (1.0f / V);
#pragma unroll
        for (int b = 0; b < 8; ++b) {
            float4 A4 = *reinterpret_cast<const float4*>(ws + OFF_A + (size_t)(b * NS + kc) * D + d);
            float yx = (A4.x - em4.x) * cm.x;
            float yy = (A4.y - em4.y) * cm.y;
            float yz = (A4.z - em4.z) * cm.z;
            float yw = (A4.w - em4.w) * cm.w;
            acc[0][b] += a0.x * yx + a0.y * yy + a0.z * yz + a0.w * yw;
            acc[1][b] += a1.x * yx + a1.y * yy + a1.z * yz + a1.w * yw;
        }
    }
#pragma unroll
    for (int r = 0; r < 2; ++r)
#pragma unroll
        for (int b = 0; b < 8; ++b) acc[r][b] = wsum(acc[r][b]);
    float v = acc[0][0];
#pragma unroll
    for (int l = 1; l < 16; ++l) if (lane == l) v = acc[l >> 3][l & 7];
    if (lane < 16) atomicAdd(&ws[OFF_YO + (lane & 7) * D + r0 + (lane >> 3)], v);
}

// ---- K7: g[b,f] = gelu(sum_d yo[b,d]*w1[f,d]).  wave per f.
// Tail blocks (768..791) init X = yo (k8 accumulates partials into X). grid 792 x 256
__global__ __launch_bounds__(256) void k7_mlp1(const float* __restrict__ w1,
                                               float* __restrict__ ws) {
    if (blockIdx.x >= 768) {
        int i = (blockIdx.x - 768) * 256 + threadIdx.x;       // < 6144
        ws[OFF_X + i] = ws[OFF_YO + i];
        return;
    }
    const int lane = threadIdx.x & 63;
    const int f = (blockIdx.x * 256 + threadIdx.x) >> 6;      // 0..3071
    float acc[8] = {0};
#pragma unroll
    for (int i = 0; i < 3; ++i) {
        int dcol = 4 * lane + 256 * i;
        float4 w = *reinterpret_cast<const float4*>(w1 + (size_t)f * D + dcol);
#pragma unroll
        for (int b = 0; b < 8; ++b) {
            float4 y = *reinterpret_cast<const float4*>(ws + OFF_YO + b * D + dcol);
            acc[b] += w.x * y.x + w.y * y.y + w.z * y.z + w.w * y.w;
        }
    }
#pragma unroll
    for (int b = 0; b < 8; ++b) acc[b] = wsum(acc[b]);
    float v = acc[0];
#pragma unroll
    for (int j = 1; j < 8; ++j) if (lane == j) v = acc[j];
    if (lane < 8) {
        float g = 0.5f * v * (1.0f + erff(v * 0.70710678118654752f));
        ws[OFF_G + lane * DFF + f] = g;
    }
}

// ---- K8: x[b,d] += sum_f g[b,f]*w2[d,f]  (X pre-initialized to yo by k7 tail).
// Wave per (d, fc): 4 f-chunks of 768 (3 iters). 3072 waves = 12/CU. grid 768 x 256
__global__ __launch_bounds__(256) void k8_mlp2(const float* __restrict__ w2,
                                               float* __restrict__ ws) {
    const int lane = threadIdx.x & 63;
    const int wid = (blockIdx.x * 256 + threadIdx.x) >> 6;    // 0..3071
    const int fc = wid & 3;
    const int dd = wid >> 2;                                  // 0..767
    const int fbase = fc * 768;
    float acc[8] = {0};
#pragma unroll
    for (int i = 0; i < 3; ++i) {
        int fcol = fbase + 4 * lane + 256 * i;
        float4 w = *reinterpret_cast<const float4*>(w2 + (size_t)dd * DFF + fcol);
#pragma unroll
        for (int b = 0; b < 8; ++b) {
            float4 g = *reinterpret_cast<const float4*>(ws + OFF_G + b * DFF + fcol);
            acc[b] += w.x * g.x + w.y * g.y + w.z * g.z + w.w * g.w;
        }
    }
#pragma unroll
    for (int b = 0; b < 8; ++b) acc[b] = wsum(acc[b]);
    float v = acc[0];
#pragma unroll
    for (int j = 1; j < 8; ++j) if (lane == j) v = acc[j];
    if (lane < 8) atomicAdd(&ws[OFF_X + lane * D + dd], v);
}

// ---- K9: logits[b,j] = x[b,:] . wte[j,:].
// CHUNKED (r9): wave owns 16 CONSECUTIVE rows (48KB contiguous wte read — page
// locality; out-line writes come consecutively from ONE wave — no cross-XCD
// 4B false sharing, which the old j+=NW stride caused). 2-deep row prefetch.
// 3142 waves needed -> grid 786 x 256.
#define K9_CHUNK 16
__global__ __launch_bounds__(256) void k9_logits(const float* __restrict__ wte,
                                                 const float* __restrict__ ws,
                                                 float* __restrict__ out) {
    const int lane = threadIdx.x & 63;
    const int wid = (blockIdx.x * 256 + threadIdx.x) >> 6;
    const int j0 = wid * K9_CHUNK;
    if (j0 >= V) return;
    const int j1 = (j0 + K9_CHUNK < V) ? j0 + K9_CHUNK : V;
    float4 xr[8][3];
#pragma unroll
    for (int b = 0; b < 8; ++b)
#pragma unroll
        for (int i = 0; i < 3; ++i)
            xr[b][i] = *reinterpret_cast<const float4*>(ws + OFF_X + b * D + 4 * lane + 256 * i);
    float4 w0[3], w1[3];
#pragma unroll
    for (int i = 0; i < 3; ++i)
        w0[i] = *reinterpret_cast<const float4*>(wte + (size_t)j0 * D + 4 * lane + 256 * i);
    {
        int jp = (j0 + 1 < j1) ? j0 + 1 : j0;
#pragma unroll
        for (int i = 0; i < 3; ++i)
            w1[i] = *reinterpret_cast<const float4*>(wte + (size_t)jp * D + 4 * lane + 256 * i);
    }
    for (int j = j0; j < j1; ++j) {
        int jp2 = (j + 2 < j1) ? j + 2 : j;                   // clamped prefetch
        float4 wn[3];
#pragma unroll
        for (int i = 0; i < 3; ++i)
            wn[i] = *reinterpret_cast<const float4*>(wte + (size_t)jp2 * D + 4 * lane + 256 * i);
        float acc[8] = {0};
#pragma unroll
        for (int b = 0; b < 8; ++b) {
#pragma unroll
            for (int i = 0; i < 3; ++i)
                acc[b] += w0[i].x * xr[b][i].x + w0[i].y * xr[b][i].y +
                          w0[i].z * xr[b][i].z + w0[i].w * xr[b][i].w;
        }
#pragma unroll
        for (int b = 0; b < 8; ++b) acc[b] = wsum(acc[b]);
        float v = acc[0];
#pragma unroll
        for (int bb = 1; bb < 8; ++bb) if (lane == bb) v = acc[bb];
        if (lane < 8) out[(size_t)lane * V + j] = v;
#pragma unroll
        for (int i = 0; i < 3; ++i) { w0[i] = w1[i]; w1[i] = wn[i]; }
    }
}

extern "C" void kernel_launch(void* const* d_in, const int* in_sizes, int n_in,
                              void* d_out, int out_size, void* d_ws, size_t ws_size,
                              hipStream_t stream) {
    const int*   idx = (const int*)  d_in[0];
    const float* wte = (const float*)d_in[1];
    const float* wpe = (const float*)d_in[2];
    const float* wq  = (const float*)d_in[3];
    const float* wk  = (const float*)d_in[4];
    const float* wv  = (const float*)d_in[5];
    const float* wlr = (const float*)d_in[6];
    const float* w_o = (const float*)d_in[7];
    const float* w1  = (const float*)d_in[8];
    const float* w2  = (const float*)d_in[9];
    float* out = (float*)d_out;
    float* ws  = (float*)d_ws;

    k2b_scores<<<256 + K2B_ZBLOCKS, 256, 0, stream>>>(wpe, wq, wk, ws);
    k14_emean_accA<<<K14_K4_BLOCKS + K14_K1_BLOCKS, 768, 0, stream>>>(idx, wte, ws);
    k6_wo     <<<1155, 256, 0, stream>>>(idx, wte, w_o, wv, wlr, ws);
    k7_mlp1   <<<792,  256, 0, stream>>>(w1, ws);
    k8_mlp2   <<<768,  256, 0, stream>>>(w2, ws);
    k9_logits <<<786,  256, 0, stream>>>(wte, ws, out);
}

// Round 11
// 334.791 us; speedup vs baseline: 1.0247x; 1.0247x over previous
//
#include <hip/hip_runtime.h>
#include <math.h>

#define B 8
#define S 1024
#define D 768
#define H 12
#define V 50257
#define DFF 3072
#define HD (H*D)      // 9216
#define SLO 1012      // first s needed (head 11, last 12 positions of y feed x row 1023)
#define NS 12

// workspace layout (float offsets)
#define OFF_EMEAN 0                     // 768   (atomic sum; divide by V on read)
#define OFF_A     768                   // B*NS*D = 73728 (atomic)
#define OFF_GQ    (OFF_A + B*NS*D)      // NS*D = 9216 (unused; kept for layout)
#define OFF_SC    (OFF_GQ + NS*D)       // NS*S = 12288 (raw scores)
#define OFF_YV    (OFF_SC + NS*S)       // B*HD = 73728 (unused; kept for layout)
#define OFF_YO    (OFF_YV + B*HD)       // B*D = 6144 (atomic)
#define OFF_G     (OFF_YO + B*D)        // B*DFF = 24576
#define OFF_X     (OFF_G + B*DFF)       // B*D = 6144 (atomic)

typedef float f4 __attribute__((ext_vector_type(4)));

__device__ __forceinline__ float wsum(float v) {
    v += __shfl_xor(v, 1, 64);
    v += __shfl_xor(v, 2, 64);
    v += __shfl_xor(v, 4, 64);
    v += __shfl_xor(v, 8, 64);
    v += __shfl_xor(v, 16, 64);
    v += __shfl_xor(v, 32, 64);
    return v;
}

__device__ __forceinline__ float wmax(float v) {
    v = fmaxf(v, __shfl_xor(v, 1, 64));
    v = fmaxf(v, __shfl_xor(v, 2, 64));
    v = fmaxf(v, __shfl_xor(v, 4, 64));
    v = fmaxf(v, __shfl_xor(v, 8, 64));
    v = fmaxf(v, __shfl_xor(v, 16, 64));
    v = fmaxf(v, __shfl_xor(v, 32, 64));
    return v;
}

// ---- K14: fused e_mean column-sum (k1 role) + softmax-inline attention
//      gather-accumulate (k4 role).
// k1 role: r7's best-measured shape (scalar-column, contiguous spans, counted
// vmcnt(8) double-batch), with `nt` (non-temporal) loads — theory: the
// ~2 TB/s read plateau is the L3 serving path (FETCH shows only half of wte
// coming from HBM); nt streams take the fast HBM path instead.
#define K14_K4_BLOCKS 256             // (32 tc, 8 b)
#define K14_K1_BLOCKS 512
#define K1_ROWS 99                    // 512*99 = 50688 >= V; batches/block = 12 or 8 (even)

#define K1_ISSUE8(T0,T1,T2,T3,T4,T5,T6,T7, P) do {                         \
    const float* _q = (P);                                                 \
    asm volatile("global_load_dword %0, %1, off nt" : "=v"(T0) : "v"(_q));    \
    asm volatile("global_load_dword %0, %1, off nt" : "=v"(T1) : "v"(_q + 1*D)); \
    asm volatile("global_load_dword %0, %1, off nt" : "=v"(T2) : "v"(_q + 2*D)); \
    asm volatile("global_load_dword %0, %1, off nt" : "=v"(T3) : "v"(_q + 3*D)); \
    asm volatile("global_load_dword %0, %1, off nt" : "=v"(T4) : "v"(_q + 4*D)); \
    asm volatile("global_load_dword %0, %1, off nt" : "=v"(T5) : "v"(_q + 5*D)); \
    asm volatile("global_load_dword %0, %1, off nt" : "=v"(T6) : "v"(_q + 6*D)); \
    asm volatile("global_load_dword %0, %1, off nt" : "=v"(T7) : "v"(_q + 7*D)); \
} while (0)

#define K1_WAIT(N, T0,T1,T2,T3,T4,T5,T6,T7) do {                           \
    asm volatile("s_waitcnt vmcnt(" #N ")"                                 \
                 : "+v"(T0), "+v"(T1), "+v"(T2), "+v"(T3),                 \
                   "+v"(T4), "+v"(T5), "+v"(T6), "+v"(T7)                  \
                 :                                                         \
                 : "memory");                                              \
    __builtin_amdgcn_sched_barrier(0);                                     \
} while (0)

__global__ __launch_bounds__(768) void k14_emean_accA(const int* __restrict__ idx,
                                                      const float* __restrict__ wte,
                                                      float* __restrict__ ws) {
    __shared__ float wl[32 * 12];
    __shared__ float mxs[12], invs[12];
    const int bid = blockIdx.x;
    const int tid = threadIdx.x;                              // 0..767 (float column)
    if (bid >= K14_K4_BLOCKS) {
        // ---- k1 role: column sums of wte rows [r0, r1)
        const int kb = bid - K14_K4_BLOCKS;
        int r0 = kb * K1_ROWS;
        if (r0 >= V) return;
        int r1 = r0 + K1_ROWS; if (r1 > V) r1 = V;
        const float* __restrict__ p = wte + (size_t)r0 * D + tid;
        const int nfull = (r1 - r0) >> 3;                     // 12 or 8 (even, >=2)
        float a0 = 0.f, a1 = 0.f, a2 = 0.f, a3 = 0.f;
        float a4 = 0.f, a5 = 0.f, a6 = 0.f, a7 = 0.f;
        float t0, t1, t2, t3, t4, t5, t6, t7;
        float u0, u1, u2, u3, u4, u5, u6, u7;
        K1_ISSUE8(t0,t1,t2,t3,t4,t5,t6,t7, p); p += 8 * D;
        for (int b2 = 0; b2 + 2 < nfull; b2 += 2) {
            K1_ISSUE8(u0,u1,u2,u3,u4,u5,u6,u7, p); p += 8 * D;
            K1_WAIT(8, t0,t1,t2,t3,t4,t5,t6,t7);
            a0 += t0; a1 += t1; a2 += t2; a3 += t3;
            a4 += t4; a5 += t5; a6 += t6; a7 += t7;
            K1_ISSUE8(t0,t1,t2,t3,t4,t5,t6,t7, p); p += 8 * D;
            K1_WAIT(8, u0,u1,u2,u3,u4,u5,u6,u7);
            a0 += u0; a1 += u1; a2 += u2; a3 += u3;
            a4 += u4; a5 += u5; a6 += u6; a7 += u7;
        }
        K1_ISSUE8(u0,u1,u2,u3,u4,u5,u6,u7, p); p += 8 * D;
        K1_WAIT(8, t0,t1,t2,t3,t4,t5,t6,t7);
        a0 += t0; a1 += t1; a2 += t2; a3 += t3;
        a4 += t4; a5 += t5; a6 += t6; a7 += t7;
        K1_WAIT(0, u0,u1,u2,u3,u4,u5,u6,u7);
        a0 += u0; a1 += u1; a2 += u2; a3 += u3;
        a4 += u4; a5 += u5; a6 += u6; a7 += u7;
        for (int r = r0 + nfull * 8; r < r1; ++r) { a0 += *p; p += D; }
        a0 += a1 + a2 + a3 + a4 + a5 + a6 + a7;
        atomicAdd(&ws[OFF_EMEAN + tid], a0);
    } else {
        // ---- k4 role: A[b,s12,:] += sum_t attn[s12,t]*wte[idx[b,t],:]
        // (softmax recomputed in-block from raw scores; cached loads — gather
        // rows benefit from L2/L3)
        const int tc = bid & 31, b = bid >> 5;
        const int w = tid >> 6, lane = tid & 63;              // wave w owns row w
        {
            const int n = SLO + w + 1;
            const float* __restrict__ sc = ws + OFF_SC + w * S;
            float m = -1e30f;
#pragma unroll
            for (int kk = 0; kk < 16; ++kk) {
                int t = kk * 64 + lane;
                if (t < n) m = fmaxf(m, sc[t]);
            }
            m = wmax(m);
            float ssum = 0.f;
#pragma unroll
            for (int kk = 0; kk < 16; ++kk) {
                int t = kk * 64 + lane;
                if (t < n) ssum += expf(sc[t] - m);
            }
            ssum = wsum(ssum);
            if (lane == 0) { mxs[w] = m; invs[w] = 1.0f / ssum; }
        }
        __syncthreads();
        if (tid < 384) {
            int tl = tid / 12, s12 = tid % 12;
            int t = tc * 32 + tl;
            float raw = ws[OFF_SC + s12 * S + t];
            wl[tid] = (t < SLO + s12 + 1) ? expf(raw - mxs[s12]) * invs[s12] : 0.0f;
        }
        __syncthreads();
        float acc[12] = {0,0,0,0,0,0,0,0,0,0,0,0};
        const int* __restrict__ ib = idx + b * S + tc * 32;
#pragma unroll 4
        for (int tl = 0; tl < 32; ++tl) {
            int row = ib[tl];
            float val = wte[(size_t)row * D + tid];
            const float* wgt = &wl[tl * 12];
#pragma unroll
            for (int s12 = 0; s12 < 12; ++s12) acc[s12] += wgt[s12] * val;
        }
#pragma unroll
        for (int s12 = 0; s12 < 12; ++s12)
            atomicAdd(&ws[OFF_A + (b * NS + s12) * D + tid], acc[s12]);
    }
}

// ---- K2b: scores[s12,t] = p[t,:] . (wpe[SLO+s12+1,:]*wq[11,:]*wk[11,:]).
// Tail blocks zero the atomic regions: [em|A] (291 blocks) and YO (24 blocks).
// grid 571 x 256
#define K2B_ZBLOCKS 315               // 291 (em+A contiguous) + 24 (YO)
__global__ __launch_bounds__(256) void k2b_scores(const float* __restrict__ wpe,
                                                  const float* __restrict__ wq,
                                                  const float* __restrict__ wk,
                                                  float* __restrict__ ws) {
    if (blockIdx.x >= 256) {
        int zb = blockIdx.x - 256;
        if (zb < 291) {
            int i = zb * 256 + threadIdx.x;                   // < 74496 = em + A
            ws[OFF_EMEAN + i] = 0.0f;
        } else {
            int i = (zb - 291) * 256 + threadIdx.x;           // < 6144 = YO
            ws[OFF_YO + i] = 0.0f;
        }
        return;
    }
    const int lane = threadIdx.x & 63;
    const int t = (blockIdx.x * 256 + threadIdx.x) >> 6;      // 0..1023
    float4 pw[3];                                             // p[t] * wq[11] * wk[11]
#pragma unroll
    for (int i = 0; i < 3; ++i) {
        int col = 4 * lane + 256 * i;
        float4 p = *reinterpret_cast<const float4*>(wpe + t * D + col);
        float4 q = *reinterpret_cast<const float4*>(wq + 11 * D + col);
        float4 k = *reinterpret_cast<const float4*>(wk + 11 * D + col);
        pw[i].x = p.x * q.x * k.x;
        pw[i].y = p.y * q.y * k.y;
        pw[i].z = p.z * q.z * k.z;
        pw[i].w = p.w * q.w * k.w;
    }
    float acc[12];
#pragma unroll
    for (int s12 = 0; s12 < 12; ++s12) {
        float a = 0.f;
#pragma unroll
        for (int i = 0; i < 3; ++i) {
            float4 g = *reinterpret_cast<const float4*>(wpe + (SLO + s12 + 1) * D + 4 * lane + 256 * i);
            a += pw[i].x * g.x + pw[i].y * g.y + pw[i].z * g.z + pw[i].w * g.w;
        }
        acc[s12] = a;
    }
#pragma unroll
    for (int s12 = 0; s12 < 12; ++s12) acc[s12] = wsum(acc[s12]);
    float v = acc[0];
#pragma unroll
    for (int j = 1; j < 12; ++j) if (lane == j) v = acc[j];
    if (lane < 12) ws[OFF_SC + lane * S + t] = v;
}

// ---- K6: yo[b,d'] += sum_f w_o[d',f] * yv[b,f], with
//      yv[b, s12*768+d] = (A[b,s12,d] - em[d])*wv[11,d]*invn[s12]*wlr[11]
// computed inline (k5 deleted). Wave per (row-pair, kc=s12).
// Tail blocks (1152..1154) atomicAdd the sb term into yo. grid 1155 x 256
__global__ __launch_bounds__(256) void k6_wo(const int* __restrict__ idx,
                                             const float* __restrict__ wte,
                                             const float* __restrict__ w_o,
                                             const float* __restrict__ wv,
                                             const float* __restrict__ wlr,
                                             float* __restrict__ ws) {
    if (blockIdx.x >= 1152) {
        int d = (blockIdx.x - 1152) * 256 + threadIdx.x;      // < 768
        float em = ws[OFF_EMEAN + d] * (1.0f / V);
        float s = 0.f;
#pragma unroll
        for (int b = 0; b < 8; ++b) {
            int row = idx[b * S + (S - 1)];
            s += wte[(size_t)row * D + d];
        }
        float sb = (s - 8.0f * em) * (1.0f / (float)S);
#pragma unroll
        for (int b = 0; b < 8; ++b) atomicAdd(&ws[OFF_YO + b * D + d], sb);
        return;
    }
    const int lane = threadIdx.x & 63;
    const int wid = (blockIdx.x * 256 + threadIdx.x) >> 6;    // 0..4607
    const int kc = wid % 12;                                  // = s12
    const int r0 = (wid / 12) * 2;                            // 0..766
    const float c1 = (1.0f / (float)(SLO + kc + 1)) * wlr[11];
    float acc[2][8] = {{0}};
#pragma unroll
    for (int i = 0; i < 3; ++i) {
        int d = 4 * lane + 256 * i;
        int k = kc * 768 + d;
        float4 a0 = *reinterpret_cast<const float4*>(w_o + (size_t)r0 * HD + k);
        float4 a1 = *reinterpret_cast<const float4*>(w_o + (size_t)(r0 + 1) * HD + k);
        float4 em4 = *reinterpret_cast<const float4*>(ws + OFF_EMEAN + d);
        float4 wv4 = *reinterpret_cast<const float4*>(wv + 11 * D + d);
        float4 cm;
        cm.x = wv4.x * c1; cm.y = wv4.y * c1; cm.z = wv4.z * c1; cm.w = wv4.w * c1;
        em4.x *= (1.0f / V); em4.y *= (1.0f / V); em4.z *= (1.0f / V); em4.w *= (1.0f / V);
#pragma unroll
        for (int b = 0; b < 8; ++b) {
            float4 A4 = *reinterpret_cast<const float4*>(ws + OFF_A + (size_t)(b * NS + kc) * D + d);
            float yx = (A4.x - em4.x) * cm.x;
            float yy = (A4.y - em4.y) * cm.y;
            float yz = (A4.z - em4.z) * cm.z;
            float yw = (A4.w - em4.w) * cm.w;
            acc[0][b] += a0.x * yx + a0.y * yy + a0.z * yz + a0.w * yw;
            acc[1][b] += a1.x * yx + a1.y * yy + a1.z * yz + a1.w * yw;
        }
    }
#pragma unroll
    for (int r = 0; r < 2; ++r)
#pragma unroll
        for (int b = 0; b < 8; ++b) acc[r][b] = wsum(acc[r][b]);
    float v = acc[0][0];
#pragma unroll
    for (int l = 1; l < 16; ++l) if (lane == l) v = acc[l >> 3][l & 7];
    if (lane < 16) atomicAdd(&ws[OFF_YO + (lane & 7) * D + r0 + (lane >> 3)], v);
}

// ---- K7: g[b,f] = gelu(sum_d yo[b,d]*w1[f,d]).  wave per f.
// Tail blocks (768..791) init X = yo (k8 accumulates partials into X). grid 792 x 256
__global__ __launch_bounds__(256) void k7_mlp1(const float* __restrict__ w1,
                                               float* __restrict__ ws) {
    if (blockIdx.x >= 768) {
        int i = (blockIdx.x - 768) * 256 + threadIdx.x;       // < 6144
        ws[OFF_X + i] = ws[OFF_YO + i];
        return;
    }
    const int lane = threadIdx.x & 63;
    const int f = (blockIdx.x * 256 + threadIdx.x) >> 6;      // 0..3071
    float acc[8] = {0};
#pragma unroll
    for (int i = 0; i < 3; ++i) {
        int dcol = 4 * lane + 256 * i;
        float4 w = *reinterpret_cast<const float4*>(w1 + (size_t)f * D + dcol);
#pragma unroll
        for (int b = 0; b < 8; ++b) {
            float4 y = *reinterpret_cast<const float4*>(ws + OFF_YO + b * D + dcol);
            acc[b] += w.x * y.x + w.y * y.y + w.z * y.z + w.w * y.w;
        }
    }
#pragma unroll
    for (int b = 0; b < 8; ++b) acc[b] = wsum(acc[b]);
    float v = acc[0];
#pragma unroll
    for (int j = 1; j < 8; ++j) if (lane == j) v = acc[j];
    if (lane < 8) {
        float g = 0.5f * v * (1.0f + erff(v * 0.70710678118654752f));
        ws[OFF_G + lane * DFF + f] = g;
    }
}

// ---- K8: x[b,d] += sum_f g[b,f]*w2[d,f]  (X pre-initialized to yo by k7 tail).
// Wave per (d, fc): 4 f-chunks of 768 (3 iters). 3072 waves = 12/CU. grid 768 x 256
__global__ __launch_bounds__(256) void k8_mlp2(const float* __restrict__ w2,
                                               float* __restrict__ ws) {
    const int lane = threadIdx.x & 63;
    const int wid = (blockIdx.x * 256 + threadIdx.x) >> 6;    // 0..3071
    const int fc = wid & 3;
    const int dd = wid >> 2;                                  // 0..767
    const int fbase = fc * 768;
    float acc[8] = {0};
#pragma unroll
    for (int i = 0; i < 3; ++i) {
        int fcol = fbase + 4 * lane + 256 * i;
        float4 w = *reinterpret_cast<const float4*>(w2 + (size_t)dd * DFF + fcol);
#pragma unroll
        for (int b = 0; b < 8; ++b) {
            float4 g = *reinterpret_cast<const float4*>(ws + OFF_G + b * DFF + fcol);
            acc[b] += w.x * g.x + w.y * g.y + w.z * g.z + w.w * g.w;
        }
    }
#pragma unroll
    for (int b = 0; b < 8; ++b) acc[b] = wsum(acc[b]);
    float v = acc[0];
#pragma unroll
    for (int j = 1; j < 8; ++j) if (lane == j) v = acc[j];
    if (lane < 8) atomicAdd(&ws[OFF_X + lane * D + dd], v);
}

// ---- K9: logits[b,j] = x[b,:] . wte[j,:].  wave per row, x in registers,
// 2-deep row prefetch (r7's best-measured strided form), wte rows loaded
// NON-TEMPORAL via ext_vector f4 (builtin requires clang vector type, not
// HIP_vector_type — r10 compile fix). grid 768 x 256
__global__ __launch_bounds__(256) void k9_logits(const float* __restrict__ wte,
                                                 const float* __restrict__ ws,
                                                 float* __restrict__ out) {
    const int lane = threadIdx.x & 63;
    const int wid = (blockIdx.x * 256 + threadIdx.x) >> 6;
    const int NW = gridDim.x * 4;
    f4 xr[8][3];
#pragma unroll
    for (int b = 0; b < 8; ++b)
#pragma unroll
        for (int i = 0; i < 3; ++i)
            xr[b][i] = *reinterpret_cast<const f4*>(ws + OFF_X + b * D + 4 * lane + 256 * i);
    f4 w0[3], w1[3];
    if (wid < V) {
#pragma unroll
        for (int i = 0; i < 3; ++i)
            w0[i] = __builtin_nontemporal_load(
                reinterpret_cast<const f4*>(wte + (size_t)wid * D + 4 * lane + 256 * i));
    }
    if (wid + NW < V) {
#pragma unroll
        for (int i = 0; i < 3; ++i)
            w1[i] = __builtin_nontemporal_load(
                reinterpret_cast<const f4*>(wte + (size_t)(wid + NW) * D + 4 * lane + 256 * i));
    }
    for (int j = wid; j < V; j += NW) {
        int jn2 = j + 2 * NW;
        f4 wn[3];
        if (jn2 < V) {
#pragma unroll
            for (int i = 0; i < 3; ++i)
                wn[i] = __builtin_nontemporal_load(
                    reinterpret_cast<const f4*>(wte + (size_t)jn2 * D + 4 * lane + 256 * i));
        }
        float acc[8] = {0};
#pragma unroll
        for (int b = 0; b < 8; ++b) {
#pragma unroll
            for (int i = 0; i < 3; ++i)
                acc[b] += w0[i].x * xr[b][i].x + w0[i].y * xr[b][i].y +
                          w0[i].z * xr[b][i].z + w0[i].w * xr[b][i].w;
        }
#pragma unroll
        for (int b = 0; b < 8; ++b) acc[b] = wsum(acc[b]);
        float v = acc[0];
#pragma unroll
        for (int bb = 1; bb < 8; ++bb) if (lane == bb) v = acc[bb];
        if (lane < 8) out[(size_t)lane * V + j] = v;
#pragma unroll
        for (int i = 0; i < 3; ++i) { w0[i] = w1[i]; w1[i] = wn[i]; }
    }
}

extern "C" void kernel_launch(void* const* d_in, const int* in_sizes, int n_in,
                              void* d_out, int out_size, void* d_ws, size_t ws_size,
                              hipStream_t stream) {
    const int*   idx = (const int*)  d_in[0];
    const float* wte = (const float*)d_in[1];
    const float* wpe = (const float*)d_in[2];
    const float* wq  = (const float*)d_in[3];
    const float* wk  = (const float*)d_in[4];
    const float* wv  = (const float*)d_in[5];
    const float* wlr = (const float*)d_in[6];
    const float* w_o = (const float*)d_in[7];
    const float* w1  = (const float*)d_in[8];
    const float* w2  = (const float*)d_in[9];
    float* out = (float*)d_out;
    float* ws  = (float*)d_ws;

    k2b_scores<<<256 + K2B_ZBLOCKS, 256, 0, stream>>>(wpe, wq, wk, ws);
    k14_emean_accA<<<K14_K4_BLOCKS + K14_K1_BLOCKS, 768, 0, stream>>>(idx, wte, ws);
    k6_wo     <<<1155, 256, 0, stream>>>(idx, wte, w_o, wv, wlr, ws);
    k7_mlp1   <<<792,  256, 0, stream>>>(w1, ws);
    k8_mlp2   <<<768,  256, 0, stream>>>(w2, ws);
    k9_logits <<<768,  256, 0, stream>>>(wte, ws, out);
}